// Round 4
// baseline (17.415 us; speedup 1.0000x reference)
//
#include <hip/hip_runtime.h>

#define EPS 1e-7f

// Block = 64 n × 4 b-waves, 8 b-iterations/thread. grid=(N/64, B/32)=1024.
// Input is staged global->LDS in 12 KB tiles (8 consecutive b-rows × 384
// floats) with fully-dense float4 loads (the direct 24 B/lane-stride float2
// pattern touched 3× the cache lines it used). Double-buffered, 1 barrier
// per 2 iterations. sigmoid(lut) tile reuses the same smem before the loop.
__global__ __launch_bounds__(256, 4) void lut_kernel(const float* __restrict__ in,
                                                     const float* __restrict__ lut,
                                                     float* __restrict__ out,
                                                     int N) {
    __shared__ __align__(16) float smem[6144];   // 24 KB: 2 × 12 KB input bufs

    const int t  = threadIdx.x;
    const int nl = t & 63;           // lane = local n
    const int w  = t >> 6;           // wave id 0..3 (parallel b)
    const int n0 = blockIdx.x * 64;
    const int n  = n0 + nl;
    const int b0base = blockIdx.y * 32;

    const size_t rowF4 = (size_t)N * 6 / 4;      // float4 per full b-row
    const float4* inF4 = reinterpret_cast<const float4*>(in);

    // per-thread float4 slots within a tile (3 of 768), constant across stages
    const size_t off0 = (size_t)(t / 96) * rowF4 + (t % 96);
    const size_t off1 = (size_t)((t + 256) / 96) * rowF4 + ((t + 256) % 96);
    const size_t off2 = (size_t)((t + 512) / 96) * rowF4 + ((t + 512) % 96);
    const size_t sbase = (size_t)b0base * rowF4 + (size_t)n0 * 6 / 4;

    // issue stage-0 loads immediately (in flight under the lut setup)
    float4 r0 = inF4[sbase + off0];
    float4 r1 = inF4[sbase + off1];
    float4 r2 = inF4[sbase + off2];

    // --- sigmoid(lut) tile -> smem (coalesced) -> w[64] registers ---
    float wreg[64];
    {
        float (*wsm)[65] = reinterpret_cast<float(*)[65]>(smem);  // 16.6 KB
        const float4* lp = reinterpret_cast<const float4*>(lut + (size_t)n0 * 64);
        const int rr = t >> 2, c4 = t & 3;
        #pragma unroll
        for (int p = 0; p < 4; ++p) {
            const int sidx = c4 + p * 4;
            float4 v = lp[rr * 16 + sidx];       // wave: 4 KB contiguous
            wsm[rr][sidx * 4 + 0] = 1.0f / (1.0f + __expf(-v.x));
            wsm[rr][sidx * 4 + 1] = 1.0f / (1.0f + __expf(-v.y));
            wsm[rr][sidx * 4 + 2] = 1.0f / (1.0f + __expf(-v.z));
            wsm[rr][sidx * 4 + 3] = 1.0f / (1.0f + __expf(-v.w));
        }
        __syncthreads();
        #pragma unroll
        for (int k = 0; k < 64; ++k)             // (nl+k)%32 banks: 2-way, free
            wreg[k] = wsm[nl][k];
        __syncthreads();                          // wsm dead; smem -> input bufs
    }

    float* op = out + (size_t)(b0base + w) * N + n;

    #pragma unroll
    for (int s = 0; s < 4; ++s) {               // stage = 2 b-iterations
        float* bcur = smem + (s & 1) * 3072;
        // write staged regs (dense b128, conflict-free)
        float4* bv = reinterpret_cast<float4*>(bcur);
        bv[t] = r0; bv[t + 256] = r1; bv[t + 512] = r2;
        // issue next stage's global loads (compiler renames regs; stays in flight)
        if (s < 3) {
            const size_t nb = sbase + (size_t)(8 * (s + 1)) * rowF4;
            r0 = inF4[nb + off0]; r1 = inF4[nb + off1]; r2 = inF4[nb + off2];
        }
        __syncthreads();   // one barrier/stage: also separates prev reads from next write

        #pragma unroll
        for (int h = 0; h < 2; ++h) {
            const int it = 2 * s + h;
            const int row = w + h * 4;           // tile row 0..7
            const float* src = bcur + row * 384 + nl * 6;
            const float x0 = src[0], x1 = src[1], x2 = src[2],
                        x3 = src[3], x4 = src[4], x5 = src[5];

            const float A0 = fmaxf(x0, 0.0f) + EPS, B0 = fmaxf(1.0f - x0, 0.0f) + EPS;
            const float A1 = fmaxf(x1, 0.0f) + EPS, B1 = fmaxf(1.0f - x1, 0.0f) + EPS;
            const float A2 = fmaxf(x2, 0.0f) + EPS, B2 = fmaxf(1.0f - x2, 0.0f) + EPS;
            const float A3 = fmaxf(x3, 0.0f) + EPS, B3 = fmaxf(1.0f - x3, 0.0f) + EPS;
            const float A4 = fmaxf(x4, 0.0f) + EPS, B4 = fmaxf(1.0f - x4, 0.0f) + EPS;
            const float A5 = fmaxf(x5, 0.0f) + EPS, B5 = fmaxf(1.0f - x5, 0.0f) + EPS;

            float t01[4];
            t01[0] = A0 * A1;  t01[1] = A0 * B1;
            t01[2] = B0 * A1;  t01[3] = B0 * B1;
            float t34[4];
            t34[0] = A3 * A4;  t34[1] = A3 * B4;
            t34[2] = B3 * A4;  t34[3] = B3 * B4;

            float tlo[8];
            #pragma unroll
            for (int hh = 0; hh < 8; ++hh)
                tlo[hh] = t34[hh >> 1] * ((hh & 1) ? B5 : A5);

            float acc = 0.0f;
            #pragma unroll
            for (int hh = 0; hh < 8; ++hh) {
                float sum = 0.0f;
                #pragma unroll
                for (int l = 0; l < 8; ++l) sum = fmaf(tlo[l], wreg[hh * 8 + l], sum);
                const float thi = t01[hh >> 1] * ((hh & 1) ? B2 : A2);
                acc = fmaf(thi, sum, acc);
            }
            op[(size_t)it * 4 * N] = acc;
        }
    }
}

extern "C" void kernel_launch(void* const* d_in, const int* in_sizes, int n_in,
                              void* d_out, int out_size, void* d_ws, size_t ws_size,
                              hipStream_t stream) {
    const float* inputs = (const float*)d_in[0];   // [B, N, 6] f32
    const float* lut    = (const float*)d_in[1];   // [N, 64]  f32
    float* out = (float*)d_out;                    // [B, N]   f32

    const int lut_sz = in_sizes[1];                // N*64
    const int N = lut_sz / 64;
    const int B = in_sizes[0] / (6 * N);

    dim3 grid(N / 64, B / 32);
    lut_kernel<<<grid, 256, 0, stream>>>(inputs, lut, out, N);
}